// Round 7
// baseline (214.392 us; speedup 1.0000x reference)
//
#include <hip/hip_runtime.h>
#include <hip/hip_bf16.h>
#include <math.h>

#define NUM_CLASSES 8192
#define FEAT_DIM    256
#define BATCH       1024
// TEMPERATURE = 0.1 -> logits = dot * 10

typedef __attribute__((ext_vector_type(8))) short bf16x8;
typedef __attribute__((ext_vector_type(4))) float f32x4;

#define GLD16(gp, lp) __builtin_amdgcn_global_load_lds(                       \
    (const __attribute__((address_space(1))) void*)(gp),                      \
    (__attribute__((address_space(3))) void*)(lp), 16, 0, 0)

__device__ __forceinline__ unsigned short f2bf(float x) {
  unsigned u = __float_as_uint(x);
  return (unsigned short)((u + 0x7fffu + ((u >> 16) & 1u)) >> 16);
}

// ---------------------------------------------------------------------------
// Phase 0: build CSR (per-class, batch-ordered update list) + zero rowsum
// and the gemm done-counter.
// ---------------------------------------------------------------------------
__global__ __launch_bounds__(1024) void prep_kernel(
    const int* __restrict__ labels, int* __restrict__ offs,
    int* __restrict__ order, float* __restrict__ rowsum,
    unsigned int* __restrict__ dctr) {
  __shared__ int lab_s[BATCH];
  __shared__ int cnt_s[NUM_CLASSES];   // counts, later offsets (32 KB)
  __shared__ int wtot[16];
  const int tid = threadIdx.x;

  if (tid == 0) *dctr = 0u;
#pragma unroll
  for (int k = 0; k < NUM_CLASSES / 1024; ++k) {
    cnt_s[k * 1024 + tid] = 0;
    rowsum[k * 1024 + tid] = 0.0f;
  }
  lab_s[tid] = labels[tid];
  __syncthreads();

  const int lab = lab_s[tid];
  int rank = 0;                         // order among same-label earlier entries
  for (int t = 0; t < tid; ++t) rank += (lab_s[t] == lab);
  atomicAdd(&cnt_s[lab], 1);
  __syncthreads();

  // prefix sum over 8192 counts: each thread owns 8
  const int base = tid * 8;
  int local[8];
  int s = 0;
#pragma unroll
  for (int k = 0; k < 8; ++k) { local[k] = s; s += cnt_s[base + k]; }
  __syncthreads();

  int x = s;
#pragma unroll
  for (int d = 1; d < 64; d <<= 1) {
    int y = __shfl_up(x, d);
    if ((tid & 63) >= d) x += y;
  }
  if ((tid & 63) == 63) wtot[tid >> 6] = x;
  __syncthreads();
  if (tid < 16) {
    int w = wtot[tid];
#pragma unroll
    for (int d = 1; d < 16; d <<= 1) {
      int y = __shfl_up(w, d);
      if (tid >= d) w += y;
    }
    wtot[tid] = w;
  }
  __syncthreads();
  const int wbase = (tid >= 64) ? wtot[(tid >> 6) - 1] : 0;
  const int excl  = wbase + x - s;

#pragma unroll
  for (int k = 0; k < 8; ++k) {
    const int o = excl + local[k];
    cnt_s[base + k] = o;
    offs[base + k]  = o;
  }
  if (tid == 1023) offs[NUM_CLASSES] = BATCH;
  __syncthreads();

  order[cnt_s[lab] + rank] = tid;
}

// ---------------------------------------------------------------------------
// Phase 1: per-class EMA update (CSR-driven) + bf16 convert.
// ---------------------------------------------------------------------------
__global__ __launch_bounds__(256) void ema_convert_kernel(
    const float* __restrict__ feats, const float* __restrict__ proto,
    const int* __restrict__ offs, const int* __restrict__ order,
    unsigned short* __restrict__ Pb) {
  const int c    = (blockIdx.x << 2) + (threadIdx.x >> 6);
  const int lane = threadIdx.x & 63;

  float4 p = ((const float4*)(proto + (size_t)c * FEAT_DIM))[lane];

  const int qs = offs[c], qe = offs[c + 1];
  for (int q = qs; q < qe; ++q) {
    const int t = order[q];
    float4 f = ((const float4*)(feats + (size_t)t * FEAT_DIM))[lane];
    float4 r;
    r.x = 0.5f * p.x + 0.5f * f.x;
    r.y = 0.5f * p.y + 0.5f * f.y;
    r.z = 0.5f * p.z + 0.5f * f.z;
    r.w = 0.5f * p.w + 0.5f * f.w;
    float ss = r.x * r.x + r.y * r.y + r.z * r.z + r.w * r.w;
#pragma unroll
    for (int off = 32; off; off >>= 1) ss += __shfl_xor(ss, off);
    float inv = 1.0f / fmaxf(sqrtf(ss), 1e-12f);
    p.x = r.x * inv; p.y = r.y * inv; p.z = r.z * inv; p.w = r.w * inv;
  }

  ushort4 u;
  u.x = f2bf(p.x); u.y = f2bf(p.y); u.z = f2bf(p.z); u.w = f2bf(p.w);
  ((ushort4*)(Pb + (size_t)c * FEAT_DIM))[lane] = u;
}

// ---------------------------------------------------------------------------
// Phase 2: fused GEMM (P * P^T / T) -> exp -> mask -> row sums -> (last
// block) final loss reduction.
// R2's proven 128x128 / BK=64 / 4-wave geometry (LROW=128B + 3-bit XOR
// swizzle = the only measured conflict-free read pattern), upgraded with the
// T3 minimum 2-phase template (m248): double-buffered LDS (64 KB), STAGE of
// tile kt+1 issued BEFORE compute(kt), and exactly ONE __syncthreads per
// tile placed AFTER compute -- the compiler's automatic vmcnt(0) drain then
// lands after the MFMA phase, so prefetch latency hides under compute.
// Race-safe: reads of buffer b retire before the barrier that precedes the
// next overwrite of b. Triangular grid + bijective XCD swizzle (2080=8x260).
// ---------------------------------------------------------------------------
#define BM 128
#define BK 64
#define NB (NUM_CLASSES / BM)           // 64 block-rows
#define NTRI (NB * (NB + 1) / 2)        // 2080 triangular blocks
#define LROW (BK * 2)                   // 128 bytes per LDS row

__global__ __launch_bounds__(256, 2) void gemm_rowsum_kernel(
    const unsigned short* __restrict__ P, float* __restrict__ rowsum,
    unsigned int* __restrict__ dctr, float* __restrict__ out) {
  __shared__ __align__(16) char lds[2][2][BM * LROW];  // [buf][A/B][16KB]=64KB
  __shared__ unsigned last_flag;
  __shared__ float red_s[4];

  // XCD-aware bijective swizzle: 2080 = 8 * 260
  const int hw  = blockIdx.x;
  const int bid = (hw & 7) * (NTRI / 8) + (hw >> 3);

  // triangular block mapping: bid -> (bi, bj), bi <= bj
  int rem = bid, bi = 0;
  while (rem >= (NB - bi)) { rem -= (NB - bi); ++bi; }
  const int bj = bi + rem;

  const int tid  = threadIdx.x;
  const int wid  = tid >> 6;          // 0..3
  const int lane = tid & 63;
  const int wm   = wid >> 1;          // 0..1
  const int wn   = wid & 1;           // 0..1

  f32x4 acc[4][4] = {};

  // staging geometry (R2-proven): 16 x 1KB wave-loads per tile per array.
  const int rloc = lane >> 3;             // 0..7 row within 8-row load
  const int csrc = (lane & 7) ^ rloc;     // pre-swizzled source chunk
  const unsigned short* PA = P + (size_t)(bi * BM) * FEAT_DIM;
  const unsigned short* PB = P + (size_t)(bj * BM) * FEAT_DIM;

#define STAGE(kt, buf)                                                        \
  {                                                                           \
    _Pragma("unroll")                                                         \
    for (int q = 0; q < 4; ++q) {                                             \
      const int L = wid * 4 + q;          /* 0..15 */                         \
      const int r = L * 8 + rloc;         /* tile row 0..127 */               \
      const size_t go = (size_t)r * FEAT_DIM + (kt) * BK + csrc * 8;          \
      GLD16(PA + go, &lds[buf][0][L * 1024]);                                 \
      GLD16(PB + go, &lds[buf][1][L * 1024]);                                 \
    }                                                                         \
  }

  const int g  = lane >> 4;   // 0..3
  const int rl = lane & 15;   // 0..15

#define COMPUTE(buf)                                                          \
  {                                                                           \
    const char* As = lds[buf][0];                                             \
    const char* Bs = lds[buf][1];                                             \
    _Pragma("unroll")                                                         \
    for (int kk = 0; kk < 2; ++kk) {                                          \
      bf16x8 a[4], b[4];                                                      \
      _Pragma("unroll")                                                       \
      for (int mi = 0; mi < 4; ++mi) {                                        \
        const int row   = wm * 64 + mi * 16 + rl;                             \
        const int chunk = (kk * 4 + g) ^ (row & 7);                           \
        a[mi] = *(const bf16x8*)(As + row * LROW + chunk * 16);               \
      }                                                                       \
      _Pragma("unroll")                                                       \
      for (int ni = 0; ni < 4; ++ni) {                                        \
        const int row   = wn * 64 + ni * 16 + rl;                             \
        const int chunk = (kk * 4 + g) ^ (row & 7);                           \
        b[ni] = *(const bf16x8*)(Bs + row * LROW + chunk * 16);               \
      }                                                                       \
      _Pragma("unroll")                                                       \
      for (int mi = 0; mi < 4; ++mi)                                          \
        _Pragma("unroll")                                                     \
        for (int ni = 0; ni < 4; ++ni)                                        \
          acc[mi][ni] = __builtin_amdgcn_mfma_f32_16x16x32_bf16(              \
              a[mi], b[ni], acc[mi][ni], 0, 0, 0);                            \
    }                                                                         \
  }

  // T3 minimum 2-phase: one barrier per tile, drain AFTER compute.
  STAGE(0, 0);
  __syncthreads();          // tile 0 landed (only fully-exposed drain)
  STAGE(1, 1);
  COMPUTE(0);
  __syncthreads();          // tile1 landed (hidden under compute0); reads of buf0 done
  STAGE(2, 0);
  COMPUTE(1);
  __syncthreads();
  STAGE(3, 1);
  COMPUTE(0);
  __syncthreads();
  COMPUTE(1);               // last tile; no barrier needed before epilogue

  // Epilogue. C/D layout: col = lane&15, row = (lane>>4)*4 + reg  [m89/m91]
  const bool diag = (bi == bj);
  float col[4] = {0.0f, 0.0f, 0.0f, 0.0f};

#pragma unroll
  for (int mi = 0; mi < 4; ++mi) {
    const int growb = bi * BM + wm * 64 + mi * 16 + g * 4;
#pragma unroll
    for (int v = 0; v < 4; ++v) {
      const int grow = growb + v;
      float rs = 0.0f;
#pragma unroll
      for (int ni = 0; ni < 4; ++ni) {
        const int gcol = bj * BM + wn * 64 + ni * 16 + rl;
        float e = __expf(10.0f * acc[mi][ni][v]);
        if (diag && grow == gcol) e = 0.0f;   // mask diagonal
        rs += e;
        col[ni] += e;
      }
      rs += __shfl_xor(rs, 1);
      rs += __shfl_xor(rs, 2);
      rs += __shfl_xor(rs, 4);
      rs += __shfl_xor(rs, 8);
      if (rl == 0) atomicAdd(&rowsum[grow], rs);
    }
  }

  if (!diag) {
    // column sums -> rows of block bj (S symmetric)
#pragma unroll
    for (int ni = 0; ni < 4; ++ni) {
      float cs = col[ni];
      cs += __shfl_xor(cs, 16);
      cs += __shfl_xor(cs, 32);
      if (g == 0) {
        const int gcol = bj * BM + wn * 64 + ni * 16 + rl;
        atomicAdd(&rowsum[gcol], cs);
      }
    }
  }

  // ---- fused finalize: last finished block reduces the loss -------------
  __threadfence();                      // drain this wave's atomics (all threads)
  __syncthreads();
  if (tid == 0) {
    unsigned o = atomicAdd(dctr, 1u);
    last_flag = (o == NTRI - 1) ? 1u : 0u;
  }
  __syncthreads();
  if (last_flag) {
    float s = 0.0f;
    for (int i = tid; i < NUM_CLASSES; i += 256) {
      // atomic RMW read: coherent against other XCDs' atomics
      float v = atomicAdd(&rowsum[i], 0.0f);
      s += logf(v * (1.0f / (float)(NUM_CLASSES - 1)));
    }
#pragma unroll
    for (int off = 32; off; off >>= 1) s += __shfl_xor(s, off);
    if (lane == 0) red_s[wid] = s;
    __syncthreads();
    if (tid == 0)
      out[0] = (red_s[0] + red_s[1] + red_s[2] + red_s[3]) *
               (1.0f / (float)NUM_CLASSES);
  }
}

// ---------------------------------------------------------------------------
extern "C" void kernel_launch(void* const* d_in, const int* in_sizes, int n_in,
                              void* d_out, int out_size, void* d_ws, size_t ws_size,
                              hipStream_t stream) {
  const float* feats  = (const float*)d_in[0];
  const float* proto  = (const float*)d_in[1];
  const int*   labels = (const int*)d_in[2];
  float*       out    = (float*)d_out;

  char* ws = (char*)d_ws;
  unsigned short* Pb = (unsigned short*)ws;                 // 4 MB bf16 P
  size_t off = (size_t)NUM_CLASSES * FEAT_DIM * 2;
  float* rowsum = (float*)(ws + off);   off += (size_t)NUM_CLASSES * 4;
  int*   offs   = (int*)(ws + off);     off += (size_t)(NUM_CLASSES + 1) * 4;
  int*   order  = (int*)(ws + off);     off += (size_t)BATCH * 4;
  unsigned int* dctr = (unsigned int*)(ws + off);

  prep_kernel<<<1, 1024, 0, stream>>>(labels, offs, order, rowsum, dctr);
  ema_convert_kernel<<<NUM_CLASSES / 4, 256, 0, stream>>>(feats, proto, offs,
                                                          order, Pb);
  gemm_rowsum_kernel<<<NTRI, 256, 0, stream>>>(Pb, rowsum, dctr, out);
}

// Round 8
// 67.677 us; speedup vs baseline: 3.1679x; 3.1679x over previous
//
#include <hip/hip_runtime.h>
#include <hip/hip_bf16.h>
#include <math.h>

#define NUM_CLASSES 8192
#define FEAT_DIM    256
#define BATCH       1024
// TEMPERATURE = 0.1 -> logits = dot * 10

typedef __attribute__((ext_vector_type(8))) short bf16x8;
typedef __attribute__((ext_vector_type(4))) float f32x4;

#define GLD16(gp, lp) __builtin_amdgcn_global_load_lds(                       \
    (const __attribute__((address_space(1))) void*)(gp),                      \
    (__attribute__((address_space(3))) void*)(lp), 16, 0, 0)

__device__ __forceinline__ unsigned short f2bf(float x) {
  unsigned u = __float_as_uint(x);
  return (unsigned short)((u + 0x7fffu + ((u >> 16) & 1u)) >> 16);
}

// ---------------------------------------------------------------------------
// Phase 0: histogram + prefix scan -> offs; arrival-rank scatter (unordered
// within class; EMA kernel restores batch order). Zero rowsum. One block.
// The O(tid) serial rank loop from earlier rounds is GONE (~8 us saved).
// ---------------------------------------------------------------------------
__global__ __launch_bounds__(1024) void prep_kernel(
    const int* __restrict__ labels, int* __restrict__ offs,
    int* __restrict__ order, float* __restrict__ rowsum) {
  __shared__ int cnt_s[NUM_CLASSES];   // counts, later offsets (32 KB)
  __shared__ int wtot[16];
  const int tid = threadIdx.x;

#pragma unroll
  for (int k = 0; k < NUM_CLASSES / 1024; ++k) {
    cnt_s[k * 1024 + tid] = 0;
    rowsum[k * 1024 + tid] = 0.0f;
  }
  __syncthreads();

  const int lab = labels[tid];
  const int arrival = atomicAdd(&cnt_s[lab], 1);   // rank within class (unordered)
  __syncthreads();

  // prefix sum over 8192 counts: each thread owns 8
  const int base = tid * 8;
  int local[8];
  int s = 0;
#pragma unroll
  for (int k = 0; k < 8; ++k) { local[k] = s; s += cnt_s[base + k]; }
  __syncthreads();                      // all count reads done before overwrite

  int x = s;
#pragma unroll
  for (int d = 1; d < 64; d <<= 1) {
    int y = __shfl_up(x, d);
    if ((tid & 63) >= d) x += y;
  }
  if ((tid & 63) == 63) wtot[tid >> 6] = x;
  __syncthreads();
  if (tid < 16) {
    int w = wtot[tid];
#pragma unroll
    for (int d = 1; d < 16; d <<= 1) {
      int y = __shfl_up(w, d);
      if (tid >= d) w += y;
    }
    wtot[tid] = w;
  }
  __syncthreads();
  const int wbase = (tid >= 64) ? wtot[(tid >> 6) - 1] : 0;
  const int excl  = wbase + x - s;

#pragma unroll
  for (int k = 0; k < 8; ++k) {
    const int o = excl + local[k];
    cnt_s[base + k] = o;                // offsets (LDS copy for scatter)
    offs[base + k]  = o;
  }
  if (tid == 1023) offs[NUM_CLASSES] = BATCH;
  __syncthreads();

  order[cnt_s[lab] + arrival] = tid;
}

// ---------------------------------------------------------------------------
// Phase 1: per-class EMA update + bf16 convert. One wave per class.
// Batch order restored by selection-min over the tiny per-class list.
// ---------------------------------------------------------------------------
__global__ __launch_bounds__(256) void ema_convert_kernel(
    const float* __restrict__ feats, const float* __restrict__ proto,
    const int* __restrict__ offs, const int* __restrict__ order,
    unsigned short* __restrict__ Pb) {
  const int c    = (blockIdx.x << 2) + (threadIdx.x >> 6);
  const int lane = threadIdx.x & 63;

  float4 p = ((const float4*)(proto + (size_t)c * FEAT_DIM))[lane];

  const int qs = offs[c], qe = offs[c + 1];
  int prev = -1;
  for (int k = qs; k < qe; ++k) {
    // smallest batch index > prev among this class's entries (wave-uniform)
    int t = 0x7fffffff;
    for (int q = qs; q < qe; ++q) {
      const int u = order[q];
      if (u > prev && u < t) t = u;
    }
    prev = t;

    float4 f = ((const float4*)(feats + (size_t)t * FEAT_DIM))[lane];
    float4 r;
    r.x = 0.5f * p.x + 0.5f * f.x;
    r.y = 0.5f * p.y + 0.5f * f.y;
    r.z = 0.5f * p.z + 0.5f * f.z;
    r.w = 0.5f * p.w + 0.5f * f.w;
    float ss = r.x * r.x + r.y * r.y + r.z * r.z + r.w * r.w;
#pragma unroll
    for (int off = 32; off; off >>= 1) ss += __shfl_xor(ss, off);
    float inv = 1.0f / fmaxf(sqrtf(ss), 1e-12f);
    p.x = r.x * inv; p.y = r.y * inv; p.z = r.z * inv; p.w = r.w * inv;
  }

  ushort4 u;
  u.x = f2bf(p.x); u.y = f2bf(p.y); u.z = f2bf(p.z); u.w = f2bf(p.w);
  ((ushort4*)(Pb + (size_t)c * FEAT_DIM))[lane] = u;
}

// ---------------------------------------------------------------------------
// Phase 2: fused GEMM (P * P^T / T) -> exp -> mask -> row sums.
// R2's proven geometry VERBATIM (128x128, BK=64, 4 waves, single 32 KB LDS
// buffer, 2 barriers/kt, LROW=128B + 3-bit XOR swizzle = measured 0
// conflicts, ~5 blocks/CU) + 2-TASK CHAINING: each block runs 2 consecutive
// triangular tiles back-to-back (8 kt steps), and the task-0 epilogue is
// placed between STAGE-issue(task1,kt0) and its drain barrier so its
// exp/shuffle/atomic work hides one full staging drain. No fences, no
// fused finalize (R7 lesson). Grid 1040 = 8 x 130, bijective XCD swizzle.
// ---------------------------------------------------------------------------
#define BM 128
#define BK 64
#define NB (NUM_CLASSES / BM)           // 64 block-rows
#define NTRI (NB * (NB + 1) / 2)        // 2080 triangular tasks
#define NBLK (NTRI / 2)                 // 1040 blocks, 2 tasks each
#define LROW (BK * 2)                   // 128 bytes per LDS row

__global__ __launch_bounds__(256, 4) void gemm_rowsum_kernel(
    const unsigned short* __restrict__ P, float* __restrict__ rowsum) {
  __shared__ __align__(16) char As[BM * LROW];  // 16 KB
  __shared__ __align__(16) char Bs[BM * LROW];  // 16 KB

  // XCD-aware bijective swizzle: 1040 = 8 * 130
  const int hw  = blockIdx.x;
  const int bid = (hw & 7) * (NBLK / 8) + (hw >> 3);

  // task0 = 2*bid -> (bi0, bj0); task1 = task0+1 (next in row, or next diag)
  int rem = bid * 2, bi0 = 0;
  while (rem >= (NB - bi0)) { rem -= (NB - bi0); ++bi0; }
  const int bj0 = bi0 + rem;
  const int bi1 = (bj0 + 1 < NB) ? bi0 : bi0 + 1;
  const int bj1 = (bj0 + 1 < NB) ? bj0 + 1 : bi0 + 1;

  const int tid  = threadIdx.x;
  const int wid  = tid >> 6;          // 0..3
  const int lane = tid & 63;
  const int wm   = wid >> 1;          // 0..1
  const int wn   = wid & 1;           // 0..1

  f32x4 acc[4][4] = {};

  // staging geometry (R2-proven): 16 x 1KB wave-loads per tile per array.
  const int rloc = lane >> 3;             // 0..7 row within 8-row load
  const int csrc = (lane & 7) ^ rloc;     // pre-swizzled source chunk
  const unsigned short* PA = P + (size_t)(bi0 * BM) * FEAT_DIM;
  const unsigned short* PB = P + (size_t)(bj0 * BM) * FEAT_DIM;

#define STAGE(kt)                                                             \
  {                                                                           \
    _Pragma("unroll")                                                         \
    for (int q = 0; q < 4; ++q) {                                             \
      const int L = wid * 4 + q;          /* 0..15 */                         \
      const int r = L * 8 + rloc;         /* tile row 0..127 */               \
      const size_t go = (size_t)r * FEAT_DIM + (kt) * BK + csrc * 8;          \
      GLD16(PA + go, As + L * 1024);                                          \
      GLD16(PB + go, Bs + L * 1024);                                          \
    }                                                                         \
  }

  const int g  = lane >> 4;   // 0..3
  const int rl = lane & 15;   // 0..15

#define COMPUTE()                                                             \
  {                                                                           \
    _Pragma("unroll")                                                         \
    for (int kk = 0; kk < 2; ++kk) {                                          \
      bf16x8 a[4], b[4];                                                      \
      _Pragma("unroll")                                                       \
      for (int mi = 0; mi < 4; ++mi) {                                        \
        const int row   = wm * 64 + mi * 16 + rl;                             \
        const int chunk = (kk * 4 + g) ^ (row & 7);                           \
        a[mi] = *(const bf16x8*)(As + row * LROW + chunk * 16);               \
      }                                                                       \
      _Pragma("unroll")                                                       \
      for (int ni = 0; ni < 4; ++ni) {                                        \
        const int row   = wn * 64 + ni * 16 + rl;                             \
        const int chunk = (kk * 4 + g) ^ (row & 7);                           \
        b[ni] = *(const bf16x8*)(Bs + row * LROW + chunk * 16);               \
      }                                                                       \
      _Pragma("unroll")                                                       \
      for (int mi = 0; mi < 4; ++mi)                                          \
        _Pragma("unroll")                                                     \
        for (int ni = 0; ni < 4; ++ni)                                        \
          acc[mi][ni] = __builtin_amdgcn_mfma_f32_16x16x32_bf16(              \
              a[mi], b[ni], acc[mi][ni], 0, 0, 0);                            \
    }                                                                         \
  }

  // Epilogue for one task. C/D layout: col=lane&15, row=(lane>>4)*4+reg.
#define EPILOGUE(BI, BJ)                                                      \
  {                                                                           \
    const bool diag = ((BI) == (BJ));                                         \
    float col[4] = {0.0f, 0.0f, 0.0f, 0.0f};                                  \
    _Pragma("unroll")                                                         \
    for (int mi = 0; mi < 4; ++mi) {                                          \
      const int growb = (BI) * BM + wm * 64 + mi * 16 + g * 4;                \
      _Pragma("unroll")                                                       \
      for (int v = 0; v < 4; ++v) {                                           \
        const int grow = growb + v;                                           \
        float rs = 0.0f;                                                      \
        _Pragma("unroll")                                                     \
        for (int ni = 0; ni < 4; ++ni) {                                      \
          const int gcol = (BJ) * BM + wn * 64 + ni * 16 + rl;                \
          float e = __expf(10.0f * acc[mi][ni][v]);                           \
          if (diag && grow == gcol) e = 0.0f;                                 \
          rs += e;                                                            \
          col[ni] += e;                                                       \
        }                                                                     \
        rs += __shfl_xor(rs, 1);                                              \
        rs += __shfl_xor(rs, 2);                                              \
        rs += __shfl_xor(rs, 4);                                              \
        rs += __shfl_xor(rs, 8);                                              \
        if (rl == 0) atomicAdd(&rowsum[grow], rs);                            \
      }                                                                       \
    }                                                                         \
    if (!diag) {                                                              \
      _Pragma("unroll")                                                       \
      for (int ni = 0; ni < 4; ++ni) {                                        \
        float cs = col[ni];                                                   \
        cs += __shfl_xor(cs, 16);                                             \
        cs += __shfl_xor(cs, 32);                                             \
        if (g == 0) {                                                         \
          const int gcol = (BJ) * BM + wn * 64 + ni * 16 + rl;                \
          atomicAdd(&rowsum[gcol], cs);                                       \
        }                                                                     \
      }                                                                       \
    }                                                                         \
  }

  STAGE(0);
  __syncthreads();                       // tile (task0,kt0) landed

#pragma unroll
  for (int p = 0; p < 8; ++p) {          // p = task*4 + kt
    COMPUTE();
    __syncthreads();                     // all LDS reads done before restage
    if (p < 7) {
      if (p == 3) {
        // switch to task1; its kt0 stage is issued, then task0's epilogue
        // (exp/shuffle/atomics, ~700 cy) hides the staging drain.
        PA = P + (size_t)(bi1 * BM) * FEAT_DIM;
        PB = P + (size_t)(bj1 * BM) * FEAT_DIM;
        STAGE(0);
        EPILOGUE(bi0, bj0);
#pragma unroll
        for (int mi = 0; mi < 4; ++mi)
#pragma unroll
          for (int ni = 0; ni < 4; ++ni)
            acc[mi][ni] = (f32x4){0.0f, 0.0f, 0.0f, 0.0f};
      } else {
        STAGE((p + 1) & 3);
      }
      __syncthreads();                   // staged tile landed
    }
  }

  EPILOGUE(bi1, bj1);
}

// ---------------------------------------------------------------------------
// Phase 3: loss = mean(log(rowsum / 8191))
// ---------------------------------------------------------------------------
__global__ __launch_bounds__(256) void finalize_kernel(
    const float* __restrict__ rowsum, float* __restrict__ out) {
  const int tid = threadIdx.x;
  float s = 0.0f;
  for (int i = tid; i < NUM_CLASSES; i += 256) {
    s += logf(rowsum[i] * (1.0f / (float)(NUM_CLASSES - 1)));
  }
#pragma unroll
  for (int off = 32; off; off >>= 1) s += __shfl_xor(s, off);
  __shared__ float red[4];
  if ((tid & 63) == 0) red[tid >> 6] = s;
  __syncthreads();
  if (tid == 0)
    out[0] = (red[0] + red[1] + red[2] + red[3]) * (1.0f / (float)NUM_CLASSES);
}

// ---------------------------------------------------------------------------
extern "C" void kernel_launch(void* const* d_in, const int* in_sizes, int n_in,
                              void* d_out, int out_size, void* d_ws, size_t ws_size,
                              hipStream_t stream) {
  const float* feats  = (const float*)d_in[0];
  const float* proto  = (const float*)d_in[1];
  const int*   labels = (const int*)d_in[2];
  float*       out    = (float*)d_out;

  char* ws = (char*)d_ws;
  unsigned short* Pb = (unsigned short*)ws;                 // 4 MB bf16 P
  size_t off = (size_t)NUM_CLASSES * FEAT_DIM * 2;
  float* rowsum = (float*)(ws + off);   off += (size_t)NUM_CLASSES * 4;
  int*   offs   = (int*)(ws + off);     off += (size_t)(NUM_CLASSES + 1) * 4;
  int*   order  = (int*)(ws + off);

  prep_kernel<<<1, 1024, 0, stream>>>(labels, offs, order, rowsum);
  ema_convert_kernel<<<NUM_CLASSES / 4, 256, 0, stream>>>(feats, proto, offs,
                                                          order, Pb);
  gemm_rowsum_kernel<<<NBLK, 256, 0, stream>>>(Pb, rowsum);
  finalize_kernel<<<1, 256, 0, stream>>>(rowsum, out);
}

// Round 9
// 62.387 us; speedup vs baseline: 3.4365x; 1.0848x over previous
//
#include <hip/hip_runtime.h>
#include <hip/hip_bf16.h>
#include <math.h>

#define NUM_CLASSES 8192
#define FEAT_DIM    256
#define BATCH       1024
// TEMPERATURE = 0.1 -> logits = dot * 10

typedef long fp8x8;                                  // 8 fp8 in 2 VGPRs
typedef __attribute__((ext_vector_type(4))) float f32x4;

#define GLD16(gp, lp) __builtin_amdgcn_global_load_lds(                       \
    (const __attribute__((address_space(1))) void*)(gp),                      \
    (__attribute__((address_space(3))) void*)(lp), 16, 0, 0)

// ---------------------------------------------------------------------------
// Phase 0: histogram + prefix scan -> offs; arrival-rank scatter (unordered
// within class; EMA kernel restores batch order). Zero rowsum. One block.
// ---------------------------------------------------------------------------
__global__ __launch_bounds__(1024) void prep_kernel(
    const int* __restrict__ labels, int* __restrict__ offs,
    int* __restrict__ order, float* __restrict__ rowsum) {
  __shared__ int cnt_s[NUM_CLASSES];   // counts, later offsets (32 KB)
  __shared__ int wtot[16];
  const int tid = threadIdx.x;

#pragma unroll
  for (int k = 0; k < NUM_CLASSES / 1024; ++k) {
    cnt_s[k * 1024 + tid] = 0;
    rowsum[k * 1024 + tid] = 0.0f;
  }
  __syncthreads();

  const int lab = labels[tid];
  const int arrival = atomicAdd(&cnt_s[lab], 1);   // rank within class (unordered)
  __syncthreads();

  // prefix sum over 8192 counts: each thread owns 8
  const int base = tid * 8;
  int local[8];
  int s = 0;
#pragma unroll
  for (int k = 0; k < 8; ++k) { local[k] = s; s += cnt_s[base + k]; }
  __syncthreads();                      // all count reads done before overwrite

  int x = s;
#pragma unroll
  for (int d = 1; d < 64; d <<= 1) {
    int y = __shfl_up(x, d);
    if ((tid & 63) >= d) x += y;
  }
  if ((tid & 63) == 63) wtot[tid >> 6] = x;
  __syncthreads();
  if (tid < 16) {
    int w = wtot[tid];
#pragma unroll
    for (int d = 1; d < 16; d <<= 1) {
      int y = __shfl_up(w, d);
      if (tid >= d) w += y;
    }
    wtot[tid] = w;
  }
  __syncthreads();
  const int wbase = (tid >= 64) ? wtot[(tid >> 6) - 1] : 0;
  const int excl  = wbase + x - s;

#pragma unroll
  for (int k = 0; k < 8; ++k) {
    const int o = excl + local[k];
    cnt_s[base + k] = o;                // offsets (LDS copy for scatter)
    offs[base + k]  = o;
  }
  if (tid == 1023) offs[NUM_CLASSES] = BATCH;
  __syncthreads();

  order[cnt_s[lab] + arrival] = tid;
}

// ---------------------------------------------------------------------------
// Phase 1: per-class EMA update + fp8 e4m3 convert. One wave per class.
// Batch order restored by selection-min over the tiny per-class list.
// ---------------------------------------------------------------------------
__global__ __launch_bounds__(256) void ema_convert_kernel(
    const float* __restrict__ feats, const float* __restrict__ proto,
    const int* __restrict__ offs, const int* __restrict__ order,
    unsigned char* __restrict__ P8) {
  const int c    = (blockIdx.x << 2) + (threadIdx.x >> 6);
  const int lane = threadIdx.x & 63;

  float4 p = ((const float4*)(proto + (size_t)c * FEAT_DIM))[lane];

  const int qs = offs[c], qe = offs[c + 1];
  int prev = -1;
  for (int k = qs; k < qe; ++k) {
    // smallest batch index > prev among this class's entries (wave-uniform)
    int t = 0x7fffffff;
    for (int q = qs; q < qe; ++q) {
      const int u = order[q];
      if (u > prev && u < t) t = u;
    }
    prev = t;

    float4 f = ((const float4*)(feats + (size_t)t * FEAT_DIM))[lane];
    float4 r;
    r.x = 0.5f * p.x + 0.5f * f.x;
    r.y = 0.5f * p.y + 0.5f * f.y;
    r.z = 0.5f * p.z + 0.5f * f.z;
    r.w = 0.5f * p.w + 0.5f * f.w;
    float ss = r.x * r.x + r.y * r.y + r.z * r.z + r.w * r.w;
#pragma unroll
    for (int off = 32; off; off >>= 1) ss += __shfl_xor(ss, off);
    float inv = 1.0f / fmaxf(sqrtf(ss), 1e-12f);
    p.x = r.x * inv; p.y = r.y * inv; p.z = r.z * inv; p.w = r.w * inv;
  }

  // pack 4 f32 -> 4 fp8 e4m3 (OCP on gfx950), bytes in ascending-k order
  int v = __builtin_amdgcn_cvt_pk_fp8_f32(p.x, p.y, 0, false);
  v = __builtin_amdgcn_cvt_pk_fp8_f32(p.z, p.w, v, true);
  ((int*)(P8 + (size_t)c * FEAT_DIM))[lane] = v;
}

// ---------------------------------------------------------------------------
// Phase 2: fused fp8 GEMM (P * P^T / T) -> exp -> mask -> row sums.
// R8's proven structure with fp8 e4m3 staging: BK=128 fp8 keeps LROW=128B,
// so the stage geometry (16 x 1KB wave-loads, 16B-chunk XOR pre-swizzle) is
// byte-identical to the measured-conflict-free bf16 layout. K-steps per task
// drop 4->2: staged bytes per block 256->128 KB, exposed drains 7->3 (the
// task-switch drain still hidden under task-0's epilogue).
// mfma_f32_16x16x32_fp8_fp8 (same fragment shape as bf16 16x16x32, 8
// elems/lane in an i64; C/D layout shape-determined -> epilogue unchanged).
// Fragment reads are ds_read_b64; worst-case 4-way conflict ~2% of block
// time (staging-bound kernel) -- deliberately accepted.
// ---------------------------------------------------------------------------
#define BM 128
#define NB (NUM_CLASSES / BM)           // 64 block-rows
#define NTRI (NB * (NB + 1) / 2)        // 2080 triangular tasks
#define NBLK (NTRI / 2)                 // 1040 blocks, 2 tasks each
#define LROW 128                        // bytes per LDS row (128 fp8)

__global__ __launch_bounds__(256, 4) void gemm_rowsum_kernel(
    const unsigned char* __restrict__ P8, float* __restrict__ rowsum) {
  __shared__ __align__(16) char As[BM * LROW];  // 16 KB
  __shared__ __align__(16) char Bs[BM * LROW];  // 16 KB

  // XCD-aware bijective swizzle: 1040 = 8 * 130
  const int hw  = blockIdx.x;
  const int bid = (hw & 7) * (NBLK / 8) + (hw >> 3);

  // task0 = 2*bid -> (bi0, bj0); task1 = task0+1 (next in row, or next diag)
  int rem = bid * 2, bi0 = 0;
  while (rem >= (NB - bi0)) { rem -= (NB - bi0); ++bi0; }
  const int bj0 = bi0 + rem;
  const int bi1 = (bj0 + 1 < NB) ? bi0 : bi0 + 1;
  const int bj1 = (bj0 + 1 < NB) ? bj0 + 1 : bi0 + 1;

  const int tid  = threadIdx.x;
  const int wid  = tid >> 6;          // 0..3
  const int lane = tid & 63;
  const int wm   = wid >> 1;          // 0..1
  const int wn   = wid & 1;           // 0..1

  f32x4 acc[4][4] = {};

  // staging geometry: 16 x 1KB wave-loads per tile per array (8 rows x 128B
  // each); physical 16B chunk cph holds logical chunk cph ^ rloc.
  const int rloc = lane >> 3;             // 0..7 row within 8-row load
  const int csrc = (lane & 7) ^ rloc;     // pre-swizzled source chunk
  const unsigned char* PA = P8 + (size_t)(bi0 * BM) * FEAT_DIM;
  const unsigned char* PB = P8 + (size_t)(bj0 * BM) * FEAT_DIM;

#define STAGE(kt)                                                             \
  {                                                                           \
    _Pragma("unroll")                                                         \
    for (int q = 0; q < 4; ++q) {                                             \
      const int L = wid * 4 + q;          /* 0..15 */                         \
      const int r = L * 8 + rloc;         /* tile row 0..127 */               \
      const size_t go = (size_t)r * FEAT_DIM + (kt) * 128 + csrc * 16;        \
      GLD16(PA + go, As + L * 1024);                                          \
      GLD16(PB + go, Bs + L * 1024);                                          \
    }                                                                         \
  }

  const int g  = lane >> 4;   // 0..3 (k-subslice within the 32-wide MFMA K)
  const int rl = lane & 15;   // 0..15

  // per-(kk,g) physical-address helper: logical byte = kk*32 + g*8
#define COMPUTE()                                                             \
  {                                                                           \
    _Pragma("unroll")                                                         \
    for (int kk = 0; kk < 4; ++kk) {                                          \
      const int cl = 2 * kk + (g >> 1);   /* logical 16B chunk */             \
      const int ib = (g & 1) * 8;         /* inner byte */                    \
      fp8x8 a[4], b[4];                                                       \
      _Pragma("unroll")                                                       \
      for (int mi = 0; mi < 4; ++mi) {                                        \
        const int row = wm * 64 + mi * 16 + rl;                               \
        a[mi] = *(const fp8x8*)(As + row * LROW + ((cl ^ (row & 7)) << 4) + ib);\
      }                                                                       \
      _Pragma("unroll")                                                       \
      for (int ni = 0; ni < 4; ++ni) {                                        \
        const int row = wn * 64 + ni * 16 + rl;                               \
        b[ni] = *(const fp8x8*)(Bs + row * LROW + ((cl ^ (row & 7)) << 4) + ib);\
      }                                                                       \
      _Pragma("unroll")                                                       \
      for (int mi = 0; mi < 4; ++mi)                                          \
        _Pragma("unroll")                                                     \
        for (int ni = 0; ni < 4; ++ni)                                        \
          acc[mi][ni] = __builtin_amdgcn_mfma_f32_16x16x32_fp8_fp8(           \
              a[mi], b[ni], acc[mi][ni], 0, 0, 0);                            \
    }                                                                         \
  }

  // Epilogue for one task. C/D layout: col=lane&15, row=(lane>>4)*4+reg.
#define EPILOGUE(BI, BJ)                                                      \
  {                                                                           \
    const bool diag = ((BI) == (BJ));                                         \
    float col[4] = {0.0f, 0.0f, 0.0f, 0.0f};                                  \
    _Pragma("unroll")                                                         \
    for (int mi = 0; mi < 4; ++mi) {                                          \
      const int growb = (BI) * BM + wm * 64 + mi * 16 + g * 4;                \
      _Pragma("unroll")                                                       \
      for (int v = 0; v < 4; ++v) {                                           \
        const int grow = growb + v;                                           \
        float rs = 0.0f;                                                      \
        _Pragma("unroll")                                                     \
        for (int ni = 0; ni < 4; ++ni) {                                      \
          const int gcol = (BJ) * BM + wn * 64 + ni * 16 + rl;                \
          float e = __expf(10.0f * acc[mi][ni][v]);                           \
          if (diag && grow == gcol) e = 0.0f;                                 \
          rs += e;                                                            \
          col[ni] += e;                                                       \
        }                                                                     \
        rs += __shfl_xor(rs, 1);                                              \
        rs += __shfl_xor(rs, 2);                                              \
        rs += __shfl_xor(rs, 4);                                              \
        rs += __shfl_xor(rs, 8);                                              \
        if (rl == 0) atomicAdd(&rowsum[grow], rs);                            \
      }                                                                       \
    }                                                                         \
    if (!diag) {                                                              \
      _Pragma("unroll")                                                       \
      for (int ni = 0; ni < 4; ++ni) {                                        \
        float cs = col[ni];                                                   \
        cs += __shfl_xor(cs, 16);                                             \
        cs += __shfl_xor(cs, 32);                                             \
        if (g == 0) {                                                         \
          const int gcol = (BJ) * BM + wn * 64 + ni * 16 + rl;                \
          atomicAdd(&rowsum[gcol], cs);                                       \
        }                                                                     \
      }                                                                       \
    }                                                                         \
  }

  STAGE(0);
  __syncthreads();                       // tile (task0,kt0) landed

#pragma unroll
  for (int p = 0; p < 4; ++p) {          // p = task*2 + kt
    COMPUTE();
    __syncthreads();                     // all LDS reads done before restage
    if (p < 3) {
      if (p == 1) {
        // switch to task1; its kt0 stage is issued, then task0's epilogue
        // (exp/shuffle/atomics) hides the staging drain.
        PA = P8 + (size_t)(bi1 * BM) * FEAT_DIM;
        PB = P8 + (size_t)(bj1 * BM) * FEAT_DIM;
        STAGE(0);
        EPILOGUE(bi0, bj0);
#pragma unroll
        for (int mi = 0; mi < 4; ++mi)
#pragma unroll
          for (int ni = 0; ni < 4; ++ni)
            acc[mi][ni] = (f32x4){0.0f, 0.0f, 0.0f, 0.0f};
      } else {
        STAGE(1);                        // p==0 -> t0k1; p==2 -> t1k1
      }
      __syncthreads();                   // staged tile landed
    }
  }

  EPILOGUE(bi1, bj1);
}

// ---------------------------------------------------------------------------
// Phase 3: loss = mean(log(rowsum / 8191))
// ---------------------------------------------------------------------------
__global__ __launch_bounds__(256) void finalize_kernel(
    const float* __restrict__ rowsum, float* __restrict__ out) {
  const int tid = threadIdx.x;
  float s = 0.0f;
  for (int i = tid; i < NUM_CLASSES; i += 256) {
    s += logf(rowsum[i] * (1.0f / (float)(NUM_CLASSES - 1)));
  }
#pragma unroll
  for (int off = 32; off; off >>= 1) s += __shfl_xor(s, off);
  __shared__ float red[4];
  if ((tid & 63) == 0) red[tid >> 6] = s;
  __syncthreads();
  if (tid == 0)
    out[0] = (red[0] + red[1] + red[2] + red[3]) * (1.0f / (float)NUM_CLASSES);
}

// ---------------------------------------------------------------------------
extern "C" void kernel_launch(void* const* d_in, const int* in_sizes, int n_in,
                              void* d_out, int out_size, void* d_ws, size_t ws_size,
                              hipStream_t stream) {
  const float* feats  = (const float*)d_in[0];
  const float* proto  = (const float*)d_in[1];
  const int*   labels = (const int*)d_in[2];
  float*       out    = (float*)d_out;

  char* ws = (char*)d_ws;
  unsigned char* P8 = (unsigned char*)ws;                   // 2 MB fp8 P
  size_t off = (size_t)NUM_CLASSES * FEAT_DIM;
  float* rowsum = (float*)(ws + off);   off += (size_t)NUM_CLASSES * 4;
  int*   offs   = (int*)(ws + off);     off += (size_t)(NUM_CLASSES + 1) * 4;
  int*   order  = (int*)(ws + off);

  prep_kernel<<<1, 1024, 0, stream>>>(labels, offs, order, rowsum);
  ema_convert_kernel<<<NUM_CLASSES / 4, 256, 0, stream>>>(feats, proto, offs,
                                                          order, P8);
  gemm_rowsum_kernel<<<NBLK, 256, 0, stream>>>(P8, rowsum);
  finalize_kernel<<<1, 256, 0, stream>>>(rowsum, out);
}